// Round 8
// baseline (10360.259 us; speedup 1.0000x reference)
//
#include <hip/hip_runtime.h>

#define B_ 64
#define S_ 256
#define F_ 256
#define H_ 1024

typedef __attribute__((ext_vector_type(8))) short bf16x8;
typedef __attribute__((ext_vector_type(4))) float f32x4;

#define MFMA(a, b, c) __builtin_amdgcn_mfma_f32_16x16x32_bf16(a, b, c, 0, 0, 0)
#define CBAR() asm volatile("" ::: "memory")

__device__ __forceinline__ float sig(float v) { return 1.0f / (1.0f + __expf(-v)); }
__device__ __forceinline__ float tanh_(float v) { return 1.0f - 2.0f / (__expf(2.0f * v) + 1.0f); }
__device__ __forceinline__ short bfr(float f) {  // fp32 -> bf16 RNE
    unsigned u = __float_as_uint(f);
    u += 0x7fffu + ((u >> 16) & 1u);
    return (short)(u >> 16);
}

// acquire fence: s_waitcnt + L1/L2 invalidate. Placed ONCE per ordering point,
// immediately before the dependent read burst (clustered, not mid-phase).
__device__ __forceinline__ void acqf() {
    __builtin_amdgcn_fence(__ATOMIC_ACQUIRE, "agent");
}

// agent-scope write-through 4B store (visible at coherence point)
__device__ __forceinline__ void st4(short* base, size_t byteoff, unsigned v) {
    __hip_atomic_store((unsigned*)((char*)base + byteoff), v,
                       __ATOMIC_RELAXED, __HIP_MEMORY_SCOPE_AGENT);
}

// arrival: drain own stores, then relaxed RMW on this block's line (8 contenders/line)
__device__ __forceinline__ void flag_add(unsigned* line) {
    asm volatile("s_waitcnt vmcnt(0)" ::: "memory");
    __hip_atomic_fetch_add(line, 1u, __ATOMIC_RELAXED, __HIP_MEMORY_SCOPE_AGENT);
}

// global wait on 32-line counter set (wave 0 only): lane i polls line i&31,
// butterfly-sum within 32-lane halves, compare.
__device__ __forceinline__ void flag_wait_g(unsigned* lines, int lane31, unsigned tgt) {
    for (;;) {
        unsigned s = __hip_atomic_load(&lines[lane31 * 16], __ATOMIC_RELAXED,
                                       __HIP_MEMORY_SCOPE_AGENT);
        s += __shfl_xor(s, 1);
        s += __shfl_xor(s, 2);
        s += __shfl_xor(s, 4);
        s += __shfl_xor(s, 8);
        s += __shfl_xor(s, 16);
        if (s >= tgt) break;
        __builtin_amdgcn_s_sleep(1);
    }
    CBAR();
}

// single-line wait (uniform broadcast load)
__device__ __forceinline__ void flag_wait1(unsigned* f, unsigned tgt) {
    while (__hip_atomic_load(f, __ATOMIC_RELAXED, __HIP_MEMORY_SCOPE_AGENT) < tgt)
        __builtin_amdgcn_s_sleep(1);
    CBAR();
}

// LDS step-token spin (no fabric traffic)
__device__ __forceinline__ void tok_spin(volatile unsigned* tk, unsigned v) {
    while (*tk < v) __builtin_amdgcn_s_sleep(1);
    CBAR();
}

// x pre-conversion into A-frag layout: [t][kf 8][m 4][lane 64][8]
__global__ __launch_bounds__(256) void conv_x(const float* __restrict__ x,
                                              short* __restrict__ xbf) {
    int tid = blockIdx.x * 256 + threadIdx.x;
    int lane = tid & 63;
    int m = (tid >> 6) & 3;
    int kf = (tid >> 8) & 7;
    int t = tid >> 11;
    int b = m * 16 + (lane & 15);
    int kb = kf * 32 + (lane >> 4) * 8;
    const float* src = x + ((size_t)b * S_ + t) * F_ + kb;
    float4 v0 = *(const float4*)src, v1 = *(const float4*)(src + 4);
    bf16x8 o;
    o[0] = bfr(v0.x); o[1] = bfr(v0.y); o[2] = bfr(v0.z); o[3] = bfr(v0.w);
    o[4] = bfr(v1.x); o[5] = bfr(v1.y); o[6] = bfr(v1.z); o[7] = bfr(v1.w);
    *(bf16x8*)(xbf + (size_t)tid * 8) = o;
}

__global__ void zero_f(float* __restrict__ p, int n) {
    int i = blockIdx.x * blockDim.x + threadIdx.x;
    if (i < n) p[i] = 0.0f;
}

// gate un-interleave: after 3 shfl_xor every lane holds i,f,g,o for its (b,u).
#define GATES(v)                                                        \
    float x1 = __shfl_xor((v), 1), x2 = __shfl_xor((v), 2), x3 = __shfl_xor((v), 3); \
    float aL = g1 ? x1 : (v), aH = g1 ? x3 : x2;                        \
    float bL = g1 ? (v) : x1, bH = g1 ? x2 : x3;                        \
    float i_ = g2 ? aH : aL;                                            \
    float f_ = g2 ? bH : bL;                                            \
    float gc = g2 ? aL : aH;                                            \
    float o_ = g2 ? bL : bH;                                            \
    i_ = sig(i_); f_ = sig(f_); o_ = sig(o_); gc = tanh_(gc);

// layer0 frag map: wave w, frag i -> kf. [2 x][8 h0][2 act]
__device__ __forceinline__ int kfOf(int w, int i) {
    return (i < 2) ? (w * 2 + i)
         : (i < 10) ? (16 + w * 8 + (i - 2))
         : (8 + w * 2 + (i - 10));
}

// fc + blend for output step tOut (caller has fenced via tokB)
__device__ __forceinline__ void fc_body(
    int tOut, bool writeAct, int nf, int lane, int w, int g1, int g2,
    const float* __restrict__ x, const short* __restrict__ fcA,
    const short* __restrict__ ldsC, f32x4* __restrict__ red,
    float biasC, float* areg, float* __restrict__ outp, short* __restrict__ actSt)
{
    const f32x4 zero4 = {0, 0, 0, 0};
    f32x4 acc0 = zero4, acc1 = zero4, acc2 = zero4, acc3 = zero4;
    #pragma unroll
    for (int i = 0; i < 8; ++i) {
        const int kf = w * 8 + i;
        const bf16x8 bw = *(const bf16x8*)(ldsC + ((size_t)kf * 64 + lane) * 8);
        const short* p = fcA + (size_t)kf * 2048 + lane * 8;
        bf16x8 a0 = *(const bf16x8*)(p);
        bf16x8 a1 = *(const bf16x8*)(p + 512);
        bf16x8 a2 = *(const bf16x8*)(p + 1024);
        bf16x8 a3 = *(const bf16x8*)(p + 1536);
        acc0 = MFMA(a0, bw, acc0);
        acc1 = MFMA(a1, bw, acc1);
        acc2 = MFMA(a2, bw, acc2);
        acc3 = MFMA(a3, bw, acc3);
    }
    red[(w * 4 + 0) * 64 + lane] = acc0;
    red[(w * 4 + 1) * 64 + lane] = acc1;
    red[(w * 4 + 2) * 64 + lane] = acc2;
    red[(w * 4 + 3) * 64 + lane] = acc3;
    __syncthreads();
    f32x4 s = red[(0 * 4 + w) * 64 + lane];
    s += red[(1 * 4 + w) * 64 + lane];
    s += red[(2 * 4 + w) * 64 + lane];
    s += red[(3 * 4 + w) * 64 + lane];
    const int c = nf * 16 + (lane & 15);
    #pragma unroll
    for (int r = 0; r < 4; ++r) {
        float ov = s[r] + biasC;
        int b = w * 16 + (lane >> 4) * 4 + r;
        size_t xi = ((size_t)b * S_ + tOut) * F_ + c;
        float xv = x[xi];
        float na = (tOut == 0) ? xv
                 : (1.15f * xv + 0.15f * areg[r] + 0.2f * ov) * (1.0f / 1.5f);
        areg[r] = na;
        outp[xi] = na;
        if (writeAct) {
            int nv = (int)(unsigned short)bfr(na);
            int ot = __shfl_xor(nv, 1);
            unsigned p32 = (lane & 1) ? (unsigned)((ot & 0xffff) | (nv << 16))
                                      : (unsigned)((nv & 0xffff) | (ot << 16));
            if ((lane & 1) == 0) {
                int ls = ((c & 31) >> 3) * 16 + (b & 15);
                size_t off = (size_t)((c >> 5) * 4 + w) * 1024 + (size_t)ls * 16 + (c & 7) * 2;
                st4(actSt, off, p32);
            }
        }
    }
}

__global__ __launch_bounds__(256, 1) void persist(
    const float* __restrict__ Wih0, const float* __restrict__ Whh0,
    const float* __restrict__ bih0, const float* __restrict__ bhh0,
    const float* __restrict__ Wih1, const float* __restrict__ Whh1,
    const float* __restrict__ bih1, const float* __restrict__ bhh1,
    const float* __restrict__ fcW,  const float* __restrict__ fcb,
    const float* __restrict__ x,    const short* __restrict__ xbf,
    short* __restrict__ h0A, short* __restrict__ actSt,
    short* __restrict__ hF, short* __restrict__ fcA,
    float* __restrict__ outp,
    unsigned* __restrict__ flagA, unsigned* __restrict__ flagB,
    unsigned* __restrict__ flagC)
{
    __shared__ f32x4 red[1024];     // 16 KB cross-wave reduce
    __shared__ short ldsC[16384];   // 32 KB fc weights (blocks nf<16)
    __shared__ unsigned tokA, tokB, tokC;
    const int tid = threadIdx.x, lane = tid & 63, w = tid >> 6;
    const int nf = blockIdx.x;
    const int lane31 = lane & 31;
    unsigned* lineA = &flagA[(nf >> 3) * 16];
    unsigned* lineB = &flagB[(nf >> 3) * 16];
    const int rowp = nf * 16 + (lane & 15);       // permuted gate row
    const int up = rowp >> 2, g = rowp & 3;       // up = pointwise unit
    const int g1 = lane & 1, g2 = lane & 2;
    const f32x4 zero4 = {0, 0, 0, 0};
    const int chunkA = (nf >> 3) * 4 + w;
    const int chunkL = (32 + (nf >> 3)) * 4 + w;
    const int lsBase = ((nf & 7) >> 1) * 16;
    const int pb = (nf & 1) * 4 + ((lane & 15) >> 3) * 2;

    if (tid == 0) { tokA = 0; tokB = 0; tokC = 0; }

    // ---- prologue: weights -> registers (once per call) ----
    bf16x8 wA[12];
    #pragma unroll
    for (int i = 0; i < 12; ++i) {
        int kf = kfOf(w, i);
        int k = kf * 32 + (lane >> 4) * 8;
        const float* src = (k < 512) ? (Wih0 + ((size_t)g * H_ + up) * 512 + k)
                                     : (Whh0 + ((size_t)g * H_ + up) * 1024 + (k - 512));
        #pragma unroll
        for (int j = 0; j < 8; ++j) wA[i][j] = bfr(src[j]);
    }
    bf16x8 wB[16];
    #pragma unroll
    for (int i = 0; i < 16; ++i) {
        int kf = w * 16 + i;
        int k = kf * 32 + (lane >> 4) * 8;
        const float* src = (k < 1024) ? (Wih1 + ((size_t)g * H_ + up) * 1024 + k)
                                      : (Whh1 + ((size_t)g * H_ + up) * 1024 + (k - 1024));
        #pragma unroll
        for (int j = 0; j < 8; ++j) wB[i][j] = bfr(src[j]);
    }
    const float bias0 = bih0[g * H_ + up] + bhh0[g * H_ + up];
    const float bias1 = bih1[g * H_ + up] + bhh1[g * H_ + up];
    float biasC = 0.0f;
    if (nf < 16) {
        int rowc = nf * 16 + (lane & 15);
        biasC = fcb[rowc];
        #pragma unroll
        for (int i = 0; i < 8; ++i) {
            int k = (w * 8 + i) * 32 + (lane >> 4) * 8;
            const float* src = fcW + (size_t)rowc * 1024 + k;
            short* d = ldsC + ((size_t)(w * 8 + i) * 64 + lane) * 8;
            #pragma unroll
            for (int j = 0; j < 8; ++j) d[j] = bfr(src[j]);
        }
    }
    __syncthreads();

    float cs0[4] = {0, 0, 0, 0}, cs1[4] = {0, 0, 0, 0}, areg[4] = {0, 0, 0, 0};

    for (int t = 0; t < S_; ++t) {
        const int cur = t & 1, nxt = cur ^ 1;
        const short* h0Ac = h0A + cur * 65536;
        short* h0An = h0A + nxt * 65536;
        const short* hFc = hF + cur * 131072;
        short* hFcW = hF + cur * 131072;
        short* hFn = hF + nxt * 131072;
        const unsigned ut = (unsigned)t;

        // ===== phase A part 1: x frags + h0 frags =====
        f32x4 acc0 = zero4, acc1 = zero4, acc2 = zero4, acc3 = zero4;
        #pragma unroll
        for (int i = 0; i < 10; ++i) {
            if (i == 2) { tok_spin(&tokA, ut); acqf(); }  // h0(t-1) ready; inv then read
            const int kf = kfOf(w, i);
            const short* p = (kf < 8)
                ? xbf + (size_t)t * 16384 + (size_t)kf * 2048 + lane * 8
                : h0Ac + (size_t)(kf - 16) * 2048 + lane * 8;
            bf16x8 a0 = *(const bf16x8*)(p);
            bf16x8 a1 = *(const bf16x8*)(p + 512);
            bf16x8 a2 = *(const bf16x8*)(p + 1024);
            bf16x8 a3 = *(const bf16x8*)(p + 1536);
            acc0 = MFMA(a0, wA[i], acc0);
            acc1 = MFMA(a1, wA[i], acc1);
            acc2 = MFMA(a2, wA[i], acc2);
            acc3 = MFMA(a3, wA[i], acc3);
        }

        // ===== fc of step t-1 (16 blocks; L0 partials stay live in acc regs) =====
        if (nf < 16 && t > 0) {
            if (w == 0) {
                flag_wait_g(flagB, lane31, 256u * ut);  // layer1(t-1) done chip-wide
                acqf();
                if (lane == 0) *(volatile unsigned*)&tokB = ut;
                CBAR();
            } else {
                tok_spin(&tokB, ut);
                acqf();
            }
            fc_body(t - 1, true, nf, lane, w, g1, g2, x, fcA, ldsC, red,
                    biasC, areg, outp, actSt);
            __syncthreads();                            // drain actSt stores (all waves)
            if (tid == 0) flag_add(&flagC[0]);
        }

        // ===== phase A part 2: action frags =====
        if (w == 0) {
            flag_wait1(&flagC[0], 16u * ut);            // fc(t-1) done by all 16
            acqf();
            if (lane == 0) *(volatile unsigned*)&tokC = ut;
            CBAR();
        } else {
            tok_spin(&tokC, ut);
            acqf();
        }
        #pragma unroll
        for (int i = 10; i < 12; ++i) {
            const int kf = kfOf(w, i);
            const short* p = actSt + (size_t)(kf - 8) * 2048 + lane * 8;
            bf16x8 a0 = *(const bf16x8*)(p);
            bf16x8 a1 = *(const bf16x8*)(p + 512);
            bf16x8 a2 = *(const bf16x8*)(p + 1024);
            bf16x8 a3 = *(const bf16x8*)(p + 1536);
            acc0 = MFMA(a0, wA[i], acc0);
            acc1 = MFMA(a1, wA[i], acc1);
            acc2 = MFMA(a2, wA[i], acc2);
            acc3 = MFMA(a3, wA[i], acc3);
        }
        red[(w * 4 + 0) * 64 + lane] = acc0;
        red[(w * 4 + 1) * 64 + lane] = acc1;
        red[(w * 4 + 2) * 64 + lane] = acc2;
        red[(w * 4 + 3) * 64 + lane] = acc3;
        __syncthreads();
        {
            f32x4 s = red[(0 * 4 + w) * 64 + lane];
            s += red[(1 * 4 + w) * 64 + lane];
            s += red[(2 * 4 + w) * 64 + lane];
            s += red[(3 * 4 + w) * 64 + lane];
            #pragma unroll
            for (int r = 0; r < 4; ++r) {
                float v = s[r] + bias0;
                GATES(v)
                float cn = f_ * cs0[r] + i_ * gc;
                cs0[r] = cn;
                float hn = o_ * tanh_(cn);
                int hv = (int)(unsigned short)bfr(hn);
                int ot = __shfl_xor(hv, 4);
                unsigned p32 = (lane & 4) ? (unsigned)((ot & 0xffff) | (hv << 16))
                                          : (unsigned)((hv & 0xffff) | (ot << 16));
                if ((lane & 7) == 0) {
                    int b = w * 16 + (lane >> 4) * 4 + r;
                    int ls = lsBase + (b & 15);
                    size_t off = (size_t)chunkA * 1024 + (size_t)ls * 16 + pb * 2;
                    st4(hFcW, off, p32);   // layer1 ih operand, k = up
                    st4(h0An, off, p32);   // next-step layer0 operand
                }
            }
        }
        __syncthreads();                                // drain h0n stores (all waves)
        if (tid == 0) flag_add(lineA);

        // ===== layer1: ih (waves 0,1 after flagA) | hh (waves 2,3 now, covered by tokC fence) =====
        acc0 = zero4; acc1 = zero4; acc2 = zero4; acc3 = zero4;
        if (w == 0) {
            flag_wait_g(flagA, lane31, 256u * (ut + 1u));
            acqf();
            if (lane == 0) *(volatile unsigned*)&tokA = ut + 1u;
            CBAR();
        } else if (w == 1) {
            tok_spin(&tokA, ut + 1u);
            acqf();
        }
        #pragma unroll
        for (int i = 0; i < 16; ++i) {
            const int kf = w * 16 + i;
            const short* p = hFc + (size_t)kf * 2048 + lane * 8;
            bf16x8 a0 = *(const bf16x8*)(p);
            bf16x8 a1 = *(const bf16x8*)(p + 512);
            bf16x8 a2 = *(const bf16x8*)(p + 1024);
            bf16x8 a3 = *(const bf16x8*)(p + 1536);
            acc0 = MFMA(a0, wB[i], acc0);
            acc1 = MFMA(a1, wB[i], acc1);
            acc2 = MFMA(a2, wB[i], acc2);
            acc3 = MFMA(a3, wB[i], acc3);
        }
        red[(w * 4 + 0) * 64 + lane] = acc0;
        red[(w * 4 + 1) * 64 + lane] = acc1;
        red[(w * 4 + 2) * 64 + lane] = acc2;
        red[(w * 4 + 3) * 64 + lane] = acc3;
        __syncthreads();
        {
            f32x4 s = red[(0 * 4 + w) * 64 + lane];
            s += red[(1 * 4 + w) * 64 + lane];
            s += red[(2 * 4 + w) * 64 + lane];
            s += red[(3 * 4 + w) * 64 + lane];
            #pragma unroll
            for (int r = 0; r < 4; ++r) {
                float v = s[r] + bias1;
                GATES(v)
                float cn = f_ * cs1[r] + i_ * gc;
                cs1[r] = cn;
                float hn = o_ * tanh_(cn);
                int hv = (int)(unsigned short)bfr(hn);
                int ot = __shfl_xor(hv, 4);
                unsigned p32 = (lane & 4) ? (unsigned)((ot & 0xffff) | (hv << 16))
                                          : (unsigned)((hv & 0xffff) | (ot << 16));
                if ((lane & 7) == 0) {
                    int b = w * 16 + (lane >> 4) * 4 + r;
                    int ls = lsBase + (b & 15);
                    size_t off2 = (size_t)ls * 16 + pb * 2;
                    st4(fcA, (size_t)chunkA * 1024 + off2, p32);  // fc operand
                    st4(hFn, (size_t)chunkL * 1024 + off2, p32);  // h1 state
                }
            }
        }
        __syncthreads();                                // drain h1n stores (all waves)
        if (tid == 0) flag_add(lineB);
    }

    // ===== tail: fc + blend for step 255 =====
    if (nf < 16) {
        if (w == 0) {
            flag_wait_g(flagB, lane31, 256u * 256u);
            acqf();
            if (lane == 0) *(volatile unsigned*)&tokB = 256u;
            CBAR();
        } else {
            tok_spin(&tokB, 256u);
            acqf();
        }
        fc_body(S_ - 1, false, nf, lane, w, g1, g2, x, fcA, ldsC, red,
                biasC, areg, outp, actSt);
    }
}

extern "C" void kernel_launch(void* const* d_in, const int* in_sizes, int n_in,
                              void* d_out, int out_size, void* d_ws, size_t ws_size,
                              hipStream_t stream) {
    const float* x    = (const float*)d_in[0];
    const float* Wih0 = (const float*)d_in[1];
    const float* Whh0 = (const float*)d_in[2];
    const float* bih0 = (const float*)d_in[3];
    const float* bhh0 = (const float*)d_in[4];
    const float* Wih1 = (const float*)d_in[5];
    const float* Whh1 = (const float*)d_in[6];
    const float* bih1 = (const float*)d_in[7];
    const float* bhh1 = (const float*)d_in[8];
    const float* fcW  = (const float*)d_in[9];
    const float* fcb  = (const float*)d_in[10];
    float* outp = (float*)d_out;

    char* ws = (char*)d_ws;
    short* xbf   = (short*)(ws + 0);               // 8,388,608 B
    short* h0A   = (short*)(ws + 8388608);         //   262,144 B (2 x 65536 sh)
    short* actSt = (short*)(ws + 8650752);         //    32,768 B
    short* hF    = (short*)(ws + 8683520);         //   524,288 B (2 x 131072 sh)
    short* fcA   = (short*)(ws + 9207808);         //   131,072 B
    unsigned* flagA = (unsigned*)(ws + 9338880);   // 2,048 B (32 lines x 64B)
    unsigned* flagB = (unsigned*)(ws + 9340928);   // 2,048 B (32 lines x 64B)
    unsigned* flagC = (unsigned*)(ws + 9342976);   //    64 B (1 line)

    conv_x<<<2048, 256, 0, stream>>>(x, xbf);
    zero_f<<<933, 256, 0, stream>>>((float*)(ws + 8388608), 238608);  // state + flags

    persist<<<256, 256, 0, stream>>>(Wih0, Whh0, bih0, bhh0,
                                     Wih1, Whh1, bih1, bhh1,
                                     fcW, fcb, x, xbf,
                                     h0A, actSt, hF, fcA, outp,
                                     flagA, flagB, flagC);
}

// Round 9
// 5716.732 us; speedup vs baseline: 1.8123x; 1.8123x over previous
//
#include <hip/hip_runtime.h>

#define B_ 64
#define S_ 256
#define F_ 256
#define H_ 1024

typedef __attribute__((ext_vector_type(8))) short bf16x8;
typedef __attribute__((ext_vector_type(4))) float f32x4;
typedef unsigned long long u64;

#define MFMA(a, b, c) __builtin_amdgcn_mfma_f32_16x16x32_bf16(a, b, c, 0, 0, 0)
#define CBAR() asm volatile("" ::: "memory")

__device__ __forceinline__ float sig(float v) { return 1.0f / (1.0f + __expf(-v)); }
__device__ __forceinline__ float tanh_(float v) { return 1.0f - 2.0f / (__expf(2.0f * v) + 1.0f); }
__device__ __forceinline__ short bfr(float f) {  // fp32 -> bf16 RNE
    unsigned u = __float_as_uint(f);
    u += 0x7fffu + ((u >> 16) & 1u);
    return (short)(u >> 16);
}

// agent-scope write-through 4B store (visible at coherence point)
__device__ __forceinline__ void st4(short* base, size_t byteoff, unsigned v) {
    __hip_atomic_store((unsigned*)((char*)base + byteoff), v,
                       __ATOMIC_RELAXED, __HIP_MEMORY_SCOPE_AGENT);
}

// agent-scope 16B fragment load as 2x8B atomic loads (coherence point; no fences needed)
__device__ __forceinline__ bf16x8 lda16(const short* p) {
    union { u64 q[2]; bf16x8 v; } r;
    r.q[0] = __hip_atomic_load((const u64*)p,       __ATOMIC_RELAXED, __HIP_MEMORY_SCOPE_AGENT);
    r.q[1] = __hip_atomic_load((const u64*)(p + 4), __ATOMIC_RELAXED, __HIP_MEMORY_SCOPE_AGENT);
    return r.v;
}

// arrival: (caller is past __syncthreads, which drains all waves' vmcnt)
__device__ __forceinline__ void flag_add(unsigned* line) {
    asm volatile("s_waitcnt vmcnt(0)" ::: "memory");
    __hip_atomic_fetch_add(line, 1u, __ATOMIC_RELAXED, __HIP_MEMORY_SCOPE_AGENT);
}

// global wait on 32-line counter set (wave 0 only): lane i polls line i&31,
// butterfly-sum within 32-lane halves, compare. No cache-invalidating fence.
__device__ __forceinline__ void flag_wait_g(unsigned* lines, int lane31, unsigned tgt) {
    for (;;) {
        unsigned s = __hip_atomic_load(&lines[lane31 * 16], __ATOMIC_RELAXED,
                                       __HIP_MEMORY_SCOPE_AGENT);
        s += __shfl_xor(s, 1);
        s += __shfl_xor(s, 2);
        s += __shfl_xor(s, 4);
        s += __shfl_xor(s, 8);
        s += __shfl_xor(s, 16);
        if (s >= tgt) break;
        __builtin_amdgcn_s_sleep(1);
    }
    CBAR();
}

// single-line wait (uniform broadcast load)
__device__ __forceinline__ void flag_wait1(unsigned* f, unsigned tgt) {
    while (__hip_atomic_load(f, __ATOMIC_RELAXED, __HIP_MEMORY_SCOPE_AGENT) < tgt)
        __builtin_amdgcn_s_sleep(1);
    CBAR();
}

// LDS step-token spin (no fabric traffic)
__device__ __forceinline__ void tok_spin(volatile unsigned* tk, unsigned v) {
    while (*tk < v) __builtin_amdgcn_s_sleep(1);
    CBAR();
}

// x pre-conversion into A-frag layout: [t][kf 8][m 4][lane 64][8]
__global__ __launch_bounds__(256) void conv_x(const float* __restrict__ x,
                                              short* __restrict__ xbf) {
    int tid = blockIdx.x * 256 + threadIdx.x;
    int lane = tid & 63;
    int m = (tid >> 6) & 3;
    int kf = (tid >> 8) & 7;
    int t = tid >> 11;
    int b = m * 16 + (lane & 15);
    int kb = kf * 32 + (lane >> 4) * 8;
    const float* src = x + ((size_t)b * S_ + t) * F_ + kb;
    float4 v0 = *(const float4*)src, v1 = *(const float4*)(src + 4);
    bf16x8 o;
    o[0] = bfr(v0.x); o[1] = bfr(v0.y); o[2] = bfr(v0.z); o[3] = bfr(v0.w);
    o[4] = bfr(v1.x); o[5] = bfr(v1.y); o[6] = bfr(v1.z); o[7] = bfr(v1.w);
    *(bf16x8*)(xbf + (size_t)tid * 8) = o;
}

__global__ void zero_f(float* __restrict__ p, int n) {
    int i = blockIdx.x * blockDim.x + threadIdx.x;
    if (i < n) p[i] = 0.0f;
}

// gate un-interleave: after 3 shfl_xor every lane holds i,f,g,o for its (b,u).
#define GATES(v)                                                        \
    float x1 = __shfl_xor((v), 1), x2 = __shfl_xor((v), 2), x3 = __shfl_xor((v), 3); \
    float aL = g1 ? x1 : (v), aH = g1 ? x3 : x2;                        \
    float bL = g1 ? (v) : x1, bH = g1 ? x2 : x3;                        \
    float i_ = g2 ? aH : aL;                                            \
    float f_ = g2 ? bH : bL;                                            \
    float gc = g2 ? aL : aH;                                            \
    float o_ = g2 ? bL : bH;                                            \
    i_ = sig(i_); f_ = sig(f_); o_ = sig(o_); gc = tanh_(gc);

// layer0 frag map (8 waves x 6 frags): i=0 -> x kf=w; i=1..4 -> h0 kf=16+w*4+(i-1); i=5 -> act kf=8+w
__device__ __forceinline__ int kfOf(int w, int i) {
    return (i == 0) ? w : (i < 5 ? 16 + w * 4 + (i - 1) : 8 + w);
}

// fc + blend for output step tOut. 8 waves x 4 kf; epilogue waves 0-3 (m = w).
__device__ __forceinline__ void fc_body(
    int tOut, bool writeAct, int nf, int lane, int w, int g1, int g2,
    const float* __restrict__ x, const short* __restrict__ fcA,
    const short* __restrict__ ldsC, f32x4* __restrict__ red,
    float biasC, float* areg, float* __restrict__ outp, short* __restrict__ actSt)
{
    const f32x4 zero4 = {0, 0, 0, 0};
    f32x4 acc0 = zero4, acc1 = zero4, acc2 = zero4, acc3 = zero4;
    #pragma unroll
    for (int i = 0; i < 4; ++i) {
        const int kf = w * 4 + i;
        const bf16x8 bw = *(const bf16x8*)(ldsC + ((size_t)kf * 64 + lane) * 8);
        const short* p = fcA + (size_t)kf * 2048 + lane * 8;
        bf16x8 a0 = lda16(p);
        bf16x8 a1 = lda16(p + 512);
        bf16x8 a2 = lda16(p + 1024);
        bf16x8 a3 = lda16(p + 1536);
        acc0 = MFMA(a0, bw, acc0);
        acc1 = MFMA(a1, bw, acc1);
        acc2 = MFMA(a2, bw, acc2);
        acc3 = MFMA(a3, bw, acc3);
    }
    red[(w * 4 + 0) * 64 + lane] = acc0;
    red[(w * 4 + 1) * 64 + lane] = acc1;
    red[(w * 4 + 2) * 64 + lane] = acc2;
    red[(w * 4 + 3) * 64 + lane] = acc3;
    __syncthreads();
    if (w < 4) {
        f32x4 s = red[(0 * 4 + w) * 64 + lane];
        #pragma unroll
        for (int k = 1; k < 8; ++k) s += red[(k * 4 + w) * 64 + lane];
        const int c = nf * 16 + (lane & 15);
        #pragma unroll
        for (int r = 0; r < 4; ++r) {
            float ov = s[r] + biasC;
            int b = w * 16 + (lane >> 4) * 4 + r;
            size_t xi = ((size_t)b * S_ + tOut) * F_ + c;
            float xv = x[xi];
            float na = (tOut == 0) ? xv
                     : (1.15f * xv + 0.15f * areg[r] + 0.2f * ov) * (1.0f / 1.5f);
            areg[r] = na;
            outp[xi] = na;
            if (writeAct) {
                int nv = (int)(unsigned short)bfr(na);
                int ot = __shfl_xor(nv, 1);
                unsigned p32 = (lane & 1) ? (unsigned)((ot & 0xffff) | (nv << 16))
                                          : (unsigned)((nv & 0xffff) | (ot << 16));
                if ((lane & 1) == 0) {
                    int ls = ((c & 31) >> 3) * 16 + (b & 15);
                    size_t off = (size_t)((c >> 5) * 4 + w) * 1024 + (size_t)ls * 16 + (c & 7) * 2;
                    st4(actSt, off, p32);
                }
            }
        }
    }
}

__global__ __launch_bounds__(512, 1) void persist(
    const float* __restrict__ Wih0, const float* __restrict__ Whh0,
    const float* __restrict__ bih0, const float* __restrict__ bhh0,
    const float* __restrict__ Wih1, const float* __restrict__ Whh1,
    const float* __restrict__ bih1, const float* __restrict__ bhh1,
    const float* __restrict__ fcW,  const float* __restrict__ fcb,
    const float* __restrict__ x,    const short* __restrict__ xbf,
    short* __restrict__ h0A, short* __restrict__ actSt,
    short* __restrict__ hF, short* __restrict__ fcA,
    float* __restrict__ outp,
    unsigned* __restrict__ flagA, unsigned* __restrict__ flagB,
    unsigned* __restrict__ flagC)
{
    __shared__ f32x4 red[2048];     // 32 KB cross-wave reduce (32 slots x 64 lanes)
    __shared__ short ldsC[16384];   // 32 KB fc weights (blocks nf<16)
    __shared__ unsigned tokA, tokB, tokC;
    const int tid = threadIdx.x, lane = tid & 63, w = tid >> 6;   // w in 0..7
    const int nf = blockIdx.x;
    const int lane31 = lane & 31;
    unsigned* lineA = &flagA[(nf >> 3) * 16];
    unsigned* lineB = &flagB[(nf >> 3) * 16];
    const int rowp = nf * 16 + (lane & 15);       // permuted gate row
    const int up = rowp >> 2, g = rowp & 3;       // up = pointwise unit
    const int g1 = lane & 1, g2 = lane & 2;
    const f32x4 zero4 = {0, 0, 0, 0};
    // epilogue store constants (valid for w<4, where w = m-tile index)
    const int chunkA = (nf >> 3) * 4 + w;
    const int chunkL = (32 + (nf >> 3)) * 4 + w;
    const int lsBase = ((nf & 7) >> 1) * 16;
    const int pb = (nf & 1) * 4 + ((lane & 15) >> 3) * 2;

    if (tid == 0) { tokA = 0; tokB = 0; tokC = 0; }

    // ---- prologue: weights -> registers (once per call) ----
    bf16x8 wA[6];
    #pragma unroll
    for (int i = 0; i < 6; ++i) {
        int kf = kfOf(w, i);
        int k = kf * 32 + (lane >> 4) * 8;
        const float* src = (k < 512) ? (Wih0 + ((size_t)g * H_ + up) * 512 + k)
                                     : (Whh0 + ((size_t)g * H_ + up) * 1024 + (k - 512));
        #pragma unroll
        for (int j = 0; j < 8; ++j) wA[i][j] = bfr(src[j]);
    }
    bf16x8 wB[8];
    #pragma unroll
    for (int i = 0; i < 8; ++i) {
        int kf = w * 8 + i;
        int k = kf * 32 + (lane >> 4) * 8;
        const float* src = (k < 1024) ? (Wih1 + ((size_t)g * H_ + up) * 1024 + k)
                                      : (Whh1 + ((size_t)g * H_ + up) * 1024 + (k - 1024));
        #pragma unroll
        for (int j = 0; j < 8; ++j) wB[i][j] = bfr(src[j]);
    }
    const float bias0 = bih0[g * H_ + up] + bhh0[g * H_ + up];
    const float bias1 = bih1[g * H_ + up] + bhh1[g * H_ + up];
    float biasC = 0.0f;
    if (nf < 16) {
        int rowc = nf * 16 + (lane & 15);
        biasC = fcb[rowc];
        #pragma unroll
        for (int i = 0; i < 4; ++i) {
            int kf = w * 4 + i;
            int k = kf * 32 + (lane >> 4) * 8;
            const float* src = fcW + (size_t)rowc * 1024 + k;
            short* d = ldsC + ((size_t)kf * 64 + lane) * 8;
            #pragma unroll
            for (int j = 0; j < 8; ++j) d[j] = bfr(src[j]);
        }
    }
    __syncthreads();

    float cs0[4] = {0, 0, 0, 0}, cs1[4] = {0, 0, 0, 0}, areg[4] = {0, 0, 0, 0};

    for (int t = 0; t < S_; ++t) {
        const int cur = t & 1, nxt = cur ^ 1;
        const short* h0Ac = h0A + cur * 65536;
        short* h0An = h0A + nxt * 65536;
        const short* hFc = hF + cur * 131072;
        short* hFcW = hF + cur * 131072;
        short* hFn = hF + nxt * 131072;
        const unsigned ut = (unsigned)t;

        // ===== phase A part 1: x frag + h0 frags =====
        f32x4 acc0 = zero4, acc1 = zero4, acc2 = zero4, acc3 = zero4;
        #pragma unroll
        for (int i = 0; i < 5; ++i) {
            if (i == 1) tok_spin(&tokA, ut);           // h0(t-1) ready (seen at L1(t-1))
            const int kf = kfOf(w, i);
            bf16x8 a0, a1, a2, a3;
            if (kf < 8) {                               // x: read-only, plain cached loads
                const short* p = xbf + (size_t)t * 16384 + (size_t)kf * 2048 + lane * 8;
                a0 = *(const bf16x8*)(p);
                a1 = *(const bf16x8*)(p + 512);
                a2 = *(const bf16x8*)(p + 1024);
                a3 = *(const bf16x8*)(p + 1536);
            } else {                                    // h0(t-1): cross-block, coherent
                const short* p = h0Ac + (size_t)(kf - 16) * 2048 + lane * 8;
                a0 = lda16(p);
                a1 = lda16(p + 512);
                a2 = lda16(p + 1024);
                a3 = lda16(p + 1536);
            }
            acc0 = MFMA(a0, wA[i], acc0);
            acc1 = MFMA(a1, wA[i], acc1);
            acc2 = MFMA(a2, wA[i], acc2);
            acc3 = MFMA(a3, wA[i], acc3);
        }

        // ===== fc of step t-1 (16 blocks; L0 partials stay live in regs) =====
        if (nf < 16 && t > 0) {
            if (w == 0) {
                flag_wait_g(flagB, lane31, 256u * ut);  // layer1(t-1) done chip-wide
                if (lane == 0) *(volatile unsigned*)&tokB = ut;
                CBAR();
            } else {
                tok_spin(&tokB, ut);
            }
            fc_body(t - 1, true, nf, lane, w, g1, g2, x, fcA, ldsC, red,
                    biasC, areg, outp, actSt);
            __syncthreads();                            // drain actSt stores (all waves)
            if (tid == 0) flag_add(&flagC[0]);
        }

        // ===== phase A part 2: action frag =====
        if (w == 0) {
            flag_wait1(&flagC[0], 16u * ut);            // fc(t-1) done by all 16
            if (lane == 0) *(volatile unsigned*)&tokC = ut;
            CBAR();
        } else {
            tok_spin(&tokC, ut);
        }
        {
            const int kf = kfOf(w, 5);
            const short* p = actSt + (size_t)(kf - 8) * 2048 + lane * 8;
            bf16x8 a0 = lda16(p);
            bf16x8 a1 = lda16(p + 512);
            bf16x8 a2 = lda16(p + 1024);
            bf16x8 a3 = lda16(p + 1536);
            acc0 = MFMA(a0, wA[5], acc0);
            acc1 = MFMA(a1, wA[5], acc1);
            acc2 = MFMA(a2, wA[5], acc2);
            acc3 = MFMA(a3, wA[5], acc3);
        }
        red[(w * 4 + 0) * 64 + lane] = acc0;
        red[(w * 4 + 1) * 64 + lane] = acc1;
        red[(w * 4 + 2) * 64 + lane] = acc2;
        red[(w * 4 + 3) * 64 + lane] = acc3;
        __syncthreads();
        if (w < 4) {
            f32x4 s = red[(0 * 4 + w) * 64 + lane];
            #pragma unroll
            for (int k = 1; k < 8; ++k) s += red[(k * 4 + w) * 64 + lane];
            #pragma unroll
            for (int r = 0; r < 4; ++r) {
                float v = s[r] + bias0;
                GATES(v)
                float cn = f_ * cs0[r] + i_ * gc;
                cs0[r] = cn;
                float hn = o_ * tanh_(cn);
                int hv = (int)(unsigned short)bfr(hn);
                int ot = __shfl_xor(hv, 4);
                unsigned p32 = (lane & 4) ? (unsigned)((ot & 0xffff) | (hv << 16))
                                          : (unsigned)((hv & 0xffff) | (ot << 16));
                if ((lane & 7) == 0) {
                    int b = w * 16 + (lane >> 4) * 4 + r;
                    int ls = lsBase + (b & 15);
                    size_t off = (size_t)chunkA * 1024 + (size_t)ls * 16 + pb * 2;
                    st4(hFcW, off, p32);   // layer1 ih operand, k = up
                    st4(h0An, off, p32);   // next-step layer0 operand
                }
            }
        }
        __syncthreads();                                // drain h0n stores (all waves)
        if (tid == 0) flag_add(lineA);

        // ===== layer1: ih (waves 0-3 after tokA) | hh (waves 4-7, covered via tokC) =====
        acc0 = zero4; acc1 = zero4; acc2 = zero4; acc3 = zero4;
        if (w == 0) {
            flag_wait_g(flagA, lane31, 256u * (ut + 1u));
            if (lane == 0) *(volatile unsigned*)&tokA = ut + 1u;
            CBAR();
        } else if (w < 4) {
            tok_spin(&tokA, ut + 1u);
        }
        #pragma unroll
        for (int i = 0; i < 8; ++i) {
            const int kf = w * 8 + i;
            const short* p = hFc + (size_t)kf * 2048 + lane * 8;
            bf16x8 a0 = lda16(p);
            bf16x8 a1 = lda16(p + 512);
            bf16x8 a2 = lda16(p + 1024);
            bf16x8 a3 = lda16(p + 1536);
            acc0 = MFMA(a0, wB[i], acc0);
            acc1 = MFMA(a1, wB[i], acc1);
            acc2 = MFMA(a2, wB[i], acc2);
            acc3 = MFMA(a3, wB[i], acc3);
        }
        red[(w * 4 + 0) * 64 + lane] = acc0;
        red[(w * 4 + 1) * 64 + lane] = acc1;
        red[(w * 4 + 2) * 64 + lane] = acc2;
        red[(w * 4 + 3) * 64 + lane] = acc3;
        __syncthreads();
        if (w < 4) {
            f32x4 s = red[(0 * 4 + w) * 64 + lane];
            #pragma unroll
            for (int k = 1; k < 8; ++k) s += red[(k * 4 + w) * 64 + lane];
            #pragma unroll
            for (int r = 0; r < 4; ++r) {
                float v = s[r] + bias1;
                GATES(v)
                float cn = f_ * cs1[r] + i_ * gc;
                cs1[r] = cn;
                float hn = o_ * tanh_(cn);
                int hv = (int)(unsigned short)bfr(hn);
                int ot = __shfl_xor(hv, 4);
                unsigned p32 = (lane & 4) ? (unsigned)((ot & 0xffff) | (hv << 16))
                                          : (unsigned)((hv & 0xffff) | (ot << 16));
                if ((lane & 7) == 0) {
                    int b = w * 16 + (lane >> 4) * 4 + r;
                    int ls = lsBase + (b & 15);
                    size_t off2 = (size_t)ls * 16 + pb * 2;
                    st4(fcA, (size_t)chunkA * 1024 + off2, p32);  // fc operand
                    st4(hFn, (size_t)chunkL * 1024 + off2, p32);  // h1 state
                }
            }
        }
        __syncthreads();                                // drain h1n stores (all waves)
        if (tid == 0) flag_add(lineB);
    }

    // ===== tail: fc + blend for step 255 =====
    if (nf < 16) {
        if (w == 0) {
            flag_wait_g(flagB, lane31, 256u * 256u);
            if (lane == 0) *(volatile unsigned*)&tokB = 256u;
            CBAR();
        } else {
            tok_spin(&tokB, 256u);
        }
        fc_body(S_ - 1, false, nf, lane, w, g1, g2, x, fcA, ldsC, red,
                biasC, areg, outp, actSt);
    }
}

extern "C" void kernel_launch(void* const* d_in, const int* in_sizes, int n_in,
                              void* d_out, int out_size, void* d_ws, size_t ws_size,
                              hipStream_t stream) {
    const float* x    = (const float*)d_in[0];
    const float* Wih0 = (const float*)d_in[1];
    const float* Whh0 = (const float*)d_in[2];
    const float* bih0 = (const float*)d_in[3];
    const float* bhh0 = (const float*)d_in[4];
    const float* Wih1 = (const float*)d_in[5];
    const float* Whh1 = (const float*)d_in[6];
    const float* bih1 = (const float*)d_in[7];
    const float* bhh1 = (const float*)d_in[8];
    const float* fcW  = (const float*)d_in[9];
    const float* fcb  = (const float*)d_in[10];
    float* outp = (float*)d_out;

    char* ws = (char*)d_ws;
    short* xbf   = (short*)(ws + 0);               // 8,388,608 B
    short* h0A   = (short*)(ws + 8388608);         //   262,144 B (2 x 65536 sh)
    short* actSt = (short*)(ws + 8650752);         //    32,768 B
    short* hF    = (short*)(ws + 8683520);         //   524,288 B (2 x 131072 sh)
    short* fcA   = (short*)(ws + 9207808);         //   131,072 B
    unsigned* flagA = (unsigned*)(ws + 9338880);   // 2,048 B (32 lines x 64B)
    unsigned* flagB = (unsigned*)(ws + 9340928);   // 2,048 B (32 lines x 64B)
    unsigned* flagC = (unsigned*)(ws + 9342976);   //    64 B (1 line)

    conv_x<<<2048, 256, 0, stream>>>(x, xbf);
    zero_f<<<933, 256, 0, stream>>>((float*)(ws + 8388608), 238608);  // state + flags

    persist<<<256, 512, 0, stream>>>(Wih0, Whh0, bih0, bhh0,
                                     Wih1, Whh1, bih1, bhh1,
                                     fcW, fcb, x, xbf,
                                     h0A, actSt, hF, fcA, outp,
                                     flagA, flagB, flagC);
}